// Round 5
// baseline (14.626 us; speedup 1.0000x reference)
//
#include <hip/hip_runtime.h>

namespace {
constexpr float INVL  = (float)(1.0 / (1.5 * 0.026) * 1.4426950408889634);   // inv * log2(e)
constexpr float C2L   = (float)(0.1 / (1.5 * 0.026) * 1.4426950408889634);   // VD * inv * log2(e)
constexpr float CLIPL = (float)(30.0 * 1.4426950408889634);                  // 30 * log2(e)
constexpr float SCALE = (float)(0.0005625 * 5.0e6 * 0.6931471805599453 * 0.6931471805599453); // ALPHA*TIA*ln2^2
constexpr float CUT_DELTA = (float)(4.0 * (1.5 * 0.026));   // 0.156: dropped terms <= 0.93 abs each, sum <= 267 << 2e4 threshold
}

// ONE kernel, no workspace, no theta staging. 512 blocks x 1024 threads (16 waves).
// Block: (b, row h, half-row wq). Wave = one pixel (w = wq*16 + wv), lane = oc.
// Per block: float4 min-reduce over theta (global skip cutoff, no LDS transpose);
// stage 3x18x32 x-halo -> LDS prescaled; build 54 per-position channel bitmasks.
// Compute: ~2.7 active terms/wave; per term theta is a 64-line L2 gather
// theta[lane*288+col] (rare, L2-resident). Skip error <= 288*sp(-4)^2*A*T ~ 267.
__global__ __launch_bounds__(1024, 8) void ekv_fused(const float* __restrict__ x,
                                                     const float* __restrict__ theta,
                                                     float* __restrict__ out) {
  __shared__ float    xs[32 * 54];     // [c][pos], pos = rr*18+cl, prescaled by INVL
  __shared__ unsigned msk[54];         // per-position channel activity bits
  __shared__ float    red[16];         // per-wave theta mins

  const int blk  = blockIdx.x;
  const int wq   = blk & 1;
  const int h    = (blk >> 1) & 31;
  const int b    = blk >> 6;
  const int tid  = threadIdx.x;
  const int lane = tid & 63;
  const int wv   = tid >> 6;           // 0..15

  if (tid < 54) msk[tid] = 0u;

  // --- theta global min via float4 (coalesced, no LDS transpose) ---
  const float4* t4 = (const float4*)theta;     // 18432 floats = 4608 float4
  float mn = 1e30f;
  for (int j = tid; j < 4608; j += 1024) {
    const float4 v = t4[j];
    mn = fminf(mn, fminf(fminf(v.x, v.y), fminf(v.z, v.w)));
  }
#pragma unroll
  for (int off = 32; off; off >>= 1) mn = fminf(mn, __shfl_down(mn, off));
  if (lane == 0) red[wv] = mn;

  // --- stage x halo: rows h-1..h+1, cols wq*16-1 .. wq*16+16, zero-padded ---
  for (int j = tid; j < 1728; j += 1024) {
    const int c   = j / 54;
    const int pos = j - c * 54;
    const int rr  = pos / 18;
    const int cl  = pos - rr * 18;
    const int gh  = h - 1 + rr;
    const int gw  = wq * 16 - 1 + cl;
    float v = 0.0f;
    if ((unsigned)gh < 32u && (unsigned)gw < 32u)
      v = x[((b * 32 + c) * 32 + gh) * 32 + gw];
    xs[j] = v * INVL;
  }
  __syncthreads();

  // every thread folds the 16 wave-mins itself (broadcast LDS reads)
  float cm = red[0];
#pragma unroll
  for (int q = 1; q < 16; ++q) cm = fminf(cm, red[q]);
  const float cutl = (cm - CUT_DELTA) * INVL;

  for (int j = tid; j < 1728; j += 1024) {
    if (xs[j] > cutl) {
      const int c = j / 54;
      atomicOr(&msk[j - c * 54], 1u << c);
    }
  }
  __syncthreads();

  // --- compute: wave = pixel, lane = oc; theta gathered from L2 per active term ---
  unsigned mv[9];
#pragma unroll
  for (int p = 0; p < 9; ++p) mv[p] = msk[(p / 3) * 18 + wv + (p % 3)];

  const float* thl_base = theta + lane * 288;
  float acc = 0.0f;
#pragma unroll
  for (int r = 0; r < 3; ++r) {
#pragma unroll
    for (int dj = 0; dj < 3; ++dj) {
      unsigned m = __builtin_amdgcn_readfirstlane(mv[r * 3 + dj]);
      const int kb = r * 3 + dj;
      const int pb = r * 18 + wv + dj;
      while (m) {
        const int c = __builtin_ctz(m);
        m &= m - 1;
        const float vgl = xs[c * 54 + pb];               // uniform broadcast
        const float thl = thl_base[c * 9 + kb];          // 64-line L2 gather (rare)
        const float a1  = __builtin_fmaf(thl, -INVL, vgl);
        const float a1c = fminf(a1, CLIPL);
        const float a2c = fminf(a1 - C2L, CLIPL);
        const float e1  = __builtin_amdgcn_exp2f(a1c);
        const float e2  = __builtin_amdgcn_exp2f(a2c);
        const float l1  = __builtin_amdgcn_logf(1.0f + e1);
        const float l2  = __builtin_amdgcn_logf(1.0f + e2);
        acc = __builtin_fmaf(l1 - l2, l1 + l2, acc);
      }
    }
  }

  out[((b * 64 + lane) * 32 + h) * 32 + wq * 16 + wv] = acc * SCALE;
}

extern "C" void kernel_launch(void* const* d_in, const int* in_sizes, int n_in,
                              void* d_out, int out_size, void* d_ws, size_t ws_size,
                              hipStream_t stream) {
  const float* x     = (const float*)d_in[0];
  const float* theta = (const float*)d_in[1];
  float* out         = (float*)d_out;
  hipLaunchKernelGGL(ekv_fused, dim3(512), dim3(1024), 0, stream, x, theta, out);
}

// Round 6
// 11.122 us; speedup vs baseline: 1.3150x; 1.3150x over previous
//
#include <hip/hip_runtime.h>

namespace {
constexpr float INVL  = (float)(1.0 / (1.5 * 0.026) * 1.4426950408889634);   // inv * log2(e)
constexpr float C2L   = (float)(0.1 / (1.5 * 0.026) * 1.4426950408889634);   // VD * inv * log2(e)
constexpr float CLIPL = (float)(30.0 * 1.4426950408889634);                  // 30 * log2(e)
constexpr float SCALE = (float)(0.0005625 * 5.0e6 * 0.6931471805599453 * 0.6931471805599453); // ALPHA*TIA*ln2^2
constexpr float CUT_DELTA = (float)(4.0 * (1.5 * 0.026));   // drop terms <= 0.94 abs each; 288x bound 272 << 2e4 threshold
}

// ONE kernel, no workspace. 512 blocks x 1024 threads (16 waves), 2 blocks/CU.
// Block: (b, row h, half-row wq). Wave = one pixel (w = wq*16 + wv), lane = oc.
// theta staged via float4 (4.5 iters/thread) into LDS layout
//   ths[c4*257 + k*64 + oc]  (col = 4*c4 + k)
// -> bank index (c4 + oc) % 32: conflict-free on BOTH the c4-consecutive write
//    and the lane(=oc)-varying compute read. Global theta min folds into the
//    same pass -> skip cutoff. x halo (3x18x32) staged prescaled; 54 per-position
//    channel bitmasks; compute iterates only set bits (wave-uniform scalar loop).
// Output transposed through reused ths-LDS for coalesced 16-float row stores.
__global__ __launch_bounds__(1024, 8) void ekv_fused(const float* __restrict__ x,
                                                     const float* __restrict__ theta,
                                                     float* __restrict__ out) {
  __shared__ float    ths[18503];  // max addr 71*257+3*64+63 = 18502; 74.0 KB
  __shared__ float    xs[1728];    // [c][pos], pos = rr*18+cl, prescaled by INVL
  __shared__ unsigned msk[54];     // per-position channel activity bits
  __shared__ float    red[17];     // 16 wave mins + folded cutoff

  const int blk  = blockIdx.x;
  const int wq   = blk & 1;
  const int h    = (blk >> 1) & 31;
  const int b    = blk >> 6;
  const int tid  = threadIdx.x;
  const int lane = tid & 63;
  const int wv   = tid >> 6;           // 0..15

  if (tid < 54) msk[tid] = 0u;

  // --- theta stage (float4, 4608 chunks) + running global min ---
  const float4* t4 = (const float4*)theta;
  float mn = 1e30f;
#pragma unroll
  for (int t = 0; t < 4; ++t) {
    const int j  = t * 1024 + tid;
    const float4 v = t4[j];
    const int oc = j / 72;
    const int c4 = j - oc * 72;
    float* d = &ths[c4 * 257 + oc];
    d[0] = v.x * INVL; d[64] = v.y * INVL; d[128] = v.z * INVL; d[192] = v.w * INVL;
    mn = fminf(mn, fminf(fminf(v.x, v.y), fminf(v.z, v.w)));
  }
  if (tid < 512) {
    const int j  = 4096 + tid;
    const float4 v = t4[j];
    const int oc = j / 72;
    const int c4 = j - oc * 72;
    float* d = &ths[c4 * 257 + oc];
    d[0] = v.x * INVL; d[64] = v.y * INVL; d[128] = v.z * INVL; d[192] = v.w * INVL;
    mn = fminf(mn, fminf(fminf(v.x, v.y), fminf(v.z, v.w)));
  }
#pragma unroll
  for (int off = 32; off; off >>= 1) mn = fminf(mn, __shfl_down(mn, off));
  if (lane == 0) red[wv] = mn;

  // --- stage x halo: rows h-1..h+1, cols wq*16-1 .. wq*16+16, zero-padded ---
  for (int j = tid; j < 1728; j += 1024) {
    const int c   = j / 54;
    const int pos = j - c * 54;
    const int rr  = pos / 18;
    const int cl  = pos - rr * 18;
    const int gh  = h - 1 + rr;
    const int gw  = wq * 16 - 1 + cl;
    float v = 0.0f;
    if ((unsigned)gh < 32u && (unsigned)gw < 32u)
      v = x[((b * 32 + c) * 32 + gh) * 32 + gw];
    xs[j] = v * INVL;
  }
  __syncthreads();                               // b1: msk init, ths, xs, red

  if (tid == 0) {
    float m = red[0];
#pragma unroll
    for (int q = 1; q < 16; ++q) m = fminf(m, red[q]);
    red[16] = (m - CUT_DELTA) * INVL;            // cutoff in prescaled units
  }
  __syncthreads();                               // b2: cutoff ready

  const float cutl = red[16];
  for (int j = tid; j < 1728; j += 1024) {
    if (xs[j] > cutl) {
      const int c = j / 54;
      atomicOr(&msk[j - c * 54], 1u << c);
    }
  }
  __syncthreads();                               // b3: masks ready

  // --- compute: wave = pixel, lane = oc ---
  unsigned mv[9];
#pragma unroll
  for (int p = 0; p < 9; ++p) mv[p] = msk[(p / 3) * 18 + wv + (p % 3)];

  float acc = 0.0f;
#pragma unroll
  for (int r = 0; r < 3; ++r) {
#pragma unroll
    for (int dj = 0; dj < 3; ++dj) {
      unsigned m = __builtin_amdgcn_readfirstlane(mv[r * 3 + dj]);
      const int kb = r * 3 + dj;
      const int pb = r * 18 + wv + dj;
      while (m) {
        const int c = __builtin_ctz(m);
        m &= m - 1;
        const float vgl = xs[c * 54 + pb];                         // uniform broadcast
        const int col   = c * 9 + kb;
        const float thl = ths[(col >> 2) * 257 + (col & 3) * 64 + lane];  // 2/bank
        const float a1  = vgl - thl;
        const float a1c = fminf(a1, CLIPL);
        const float a2c = fminf(a1 - C2L, CLIPL);
        const float e1  = __builtin_amdgcn_exp2f(a1c);
        const float e2  = __builtin_amdgcn_exp2f(a2c);
        const float l1  = __builtin_amdgcn_logf(1.0f + e1);
        const float l2  = __builtin_amdgcn_logf(1.0f + e2);
        acc = __builtin_fmaf(l1 - l2, l1 + l2, acc);
      }
    }
  }

  __syncthreads();                               // b4: all ths reads done
  ths[lane * 16 + ((wv + lane) & 15)] = acc * SCALE;   // reuse ths as 1024-slot os
  __syncthreads();                               // b5: transposed tile ready

  const int oc2 = tid >> 4;
  const int wp  = tid & 15;
  out[((b * 64 + oc2) * 32 + h) * 32 + wq * 16 + wp] = ths[oc2 * 16 + ((wp + oc2) & 15)];
}

extern "C" void kernel_launch(void* const* d_in, const int* in_sizes, int n_in,
                              void* d_out, int out_size, void* d_ws, size_t ws_size,
                              hipStream_t stream) {
  const float* x     = (const float*)d_in[0];
  const float* theta = (const float*)d_in[1];
  float* out         = (float*)d_out;
  (void)d_ws; (void)ws_size; (void)in_sizes; (void)n_in; (void)out_size;
  hipLaunchKernelGGL(ekv_fused, dim3(512), dim3(1024), 0, stream, x, theta, out);
}